// Round 1
// baseline (1132.869 us; speedup 1.0000x reference)
//
#include <hip/hip_runtime.h>
#include <math.h>

#define NB 131072

// ---- workspace layout (float offsets) ----
#define WS_A_EEG 0        // [64][32]  fus_w[:, :64] @ eeg_fw
#define WS_A_EOG 2048     // [64][32]  fus_w[:, 64:] @ eog_fw
#define WS_B0    4096     // [64]      folded bias + pe0
#define WS_WATT  4160     // [2][64][64] tl_ow @ tl_vw
#define WS_BATT  12352    // [2][64]
#define WS_WVT   12480    // [62][62]  wv transposed: wvT[e][d] = wv[d][e]
#define WS_CWT   16324    // [62][32][5] cwT[c][o][l] = cw[o][c][l]
#define WS_CWOG  26244    // [33][32]  cwogT[l][o] = eog_cw[o][l]
#define WS_W2T   27300    // [2][256][64] w2T[j][c] = w2[c][j]
#define WS_TOTAL 60068

__global__ __launch_bounds__(256) void mcaf_pre(
    const float* __restrict__ eeg_inw, const float* __restrict__ eeg_cw,
    const float* __restrict__ eeg_fw,  const float* __restrict__ eeg_fb,
    const float* __restrict__ eog_cw,  const float* __restrict__ eog_fw,
    const float* __restrict__ eog_fb,
    const float* __restrict__ fus_w,   const float* __restrict__ fus_b,
    const float* __restrict__ tl_inw,  const float* __restrict__ tl_inb,
    const float* __restrict__ tl_ow,   const float* __restrict__ tl_ob,
    const float* __restrict__ tl_w2,
    float* __restrict__ ws)
{
    const int tid  = blockIdx.x * blockDim.x + threadIdx.x;
    const int nthr = gridDim.x * blockDim.x;

    // A_eeg / A_eog : [64][32]
    for (int idx = tid; idx < 2048; idx += nthr) {
        int f = idx >> 5, o = idx & 31;
        float a = 0.f, a2 = 0.f;
        for (int k = 0; k < 64; ++k) {
            a  = fmaf(fus_w[f * 128 + k],      eeg_fw[k * 32 + o], a);
            a2 = fmaf(fus_w[f * 128 + 64 + k], eog_fw[k * 32 + o], a2);
        }
        ws[WS_A_EEG + idx] = a;
        ws[WS_A_EOG + idx] = a2;
    }
    // b0 = fus_w[:, :64]@eeg_fb + fus_w[:, 64:]@eog_fb + fus_b + pe0
    for (int f = tid; f < 64; f += nthr) {
        float a = fus_b[f] + (float)(f & 1);
        for (int k = 0; k < 64; ++k) {
            a = fmaf(fus_w[f * 128 + k],      eeg_fb[k], a);
            a = fmaf(fus_w[f * 128 + 64 + k], eog_fb[k], a);
        }
        ws[WS_B0 + f] = a;
    }
    // W_attn[i][c][d] = sum_e ow[i][c][e] * inw[i][128+e][d]
    for (int idx = tid; idx < 8192; idx += nthr) {
        int i = idx >> 12, c = (idx >> 6) & 63, d = idx & 63;
        float a = 0.f;
        for (int e = 0; e < 64; ++e)
            a = fmaf(tl_ow[i * 4096 + c * 64 + e],
                     tl_inw[i * 12288 + (128 + e) * 64 + d], a);
        ws[WS_WATT + idx] = a;
    }
    for (int idx = tid; idx < 128; idx += nthr) {
        int i = idx >> 6, c = idx & 63;
        float a = tl_ob[i * 64 + c];
        for (int e = 0; e < 64; ++e)
            a = fmaf(tl_ow[i * 4096 + c * 64 + e], tl_inb[i * 192 + 128 + e], a);
        ws[WS_BATT + idx] = a;
    }
    // wvT[e][d] = eeg_inw[124+d][e]
    for (int idx = tid; idx < 3844; idx += nthr) {
        int e = idx / 62, d = idx - e * 62;
        ws[WS_WVT + idx] = eeg_inw[(124 + d) * 62 + e];
    }
    // cwT[c][o][l] = eeg_cw[o][c][l]
    for (int idx = tid; idx < 9920; idx += nthr) {
        int c = idx / 160, r = idx - c * 160;
        int o = r / 5, l = r - o * 5;
        ws[WS_CWT + idx] = eeg_cw[o * 310 + c * 5 + l];
    }
    // cwogT[l][o] = eog_cw[o][l]
    for (int idx = tid; idx < 1056; idx += nthr) {
        int l = idx >> 5, o = idx & 31;
        ws[WS_CWOG + idx] = eog_cw[o * 33 + l];
    }
    // w2T[i][j][c] = tl_w2[i][c][j]
    for (int idx = tid; idx < 32768; idx += nthr) {
        int i = idx >> 14, r = idx & 16383;
        int j = r >> 6, c = r & 63;
        ws[WS_W2T + idx] = tl_w2[i * 16384 + c * 256 + j];
    }
}

__global__ __launch_bounds__(256, 2) void mcaf_main(
    const float* __restrict__ eeg,     const float* __restrict__ eog,
    const float* __restrict__ eeg_inb,
    const float* __restrict__ eeg_ow,  const float* __restrict__ eeg_ob,
    const float* __restrict__ eog_inw, const float* __restrict__ eog_inb,
    const float* __restrict__ eog_ow,  const float* __restrict__ eog_ob,
    const float* __restrict__ eeg_cb,  const float* __restrict__ eog_cb,
    const float* __restrict__ tl_ln1_s, const float* __restrict__ tl_ln1_b,
    const float* __restrict__ tl_ln2_s, const float* __restrict__ tl_ln2_b,
    const float* __restrict__ tl_w1,   const float* __restrict__ tl_b1,
    const float* __restrict__ tl_b2,
    const float* __restrict__ fn_s,    const float* __restrict__ fn_b,
    const float* __restrict__ cls_w,   const float* __restrict__ cls_b,
    const float* __restrict__ ws,      float* __restrict__ out)
{
    // per-wave staging tile: 64 rows x 41 (40 cols + pad); 4 waves
    __shared__ float smem[4 * 64 * 41];
    const int t    = threadIdx.x;
    const int lane = t & 63;
    const int wid  = t >> 6;
    const int bw   = blockIdx.x * 256 + wid * 64;   // wave's batch base
    const int b    = bw + lane;                     // this thread's batch element
    float* sw = smem + wid * (64 * 41);

    // ================= pass 1: vbar = wv @ pooled + bv =================
    float vbar[62];
    #pragma unroll
    for (int d = 0; d < 62; ++d) vbar[d] = eeg_inb[124 + d];

    for (int chunk = 0; chunk < 8; ++chunk) {
        const int ch0 = chunk * 8;
        // coalesced stage: 64 rows x 40 cols (global cols ch0*5 .. +40)
        for (int j = 0; j < 40; ++j) {
            int idx = j * 64 + lane;
            int r = idx / 40, cc = idx - r * 40;
            int gcol = ch0 * 5 + cc;
            float v = 0.f;
            if (gcol < 310) v = eeg[(bw + r) * 310 + gcol];
            sw[r * 41 + cc] = v;
        }
        __syncthreads();
        const int nch = (62 - ch0 < 8) ? (62 - ch0) : 8;
        for (int el = 0; el < nch; ++el) {
            const int e = ch0 + el;
            const float* xr = sw + lane * 41 + el * 5;
            float p = (xr[0] + xr[1] + xr[2] + xr[3] + xr[4]) * 0.2f;
            const float* wr = ws + WS_WVT + e * 62;
            #pragma unroll
            for (int d = 0; d < 62; ++d) vbar[d] = fmaf(p, wr[d], vbar[d]);
        }
        __syncthreads();
    }

    // ================= pass 2: obar per channel + conv =================
    float h[32];
    #pragma unroll
    for (int o = 0; o < 32; ++o) h[o] = eeg_cb[o];

    for (int chunk = 0; chunk < 8; ++chunk) {
        const int ch0 = chunk * 8;
        for (int j = 0; j < 40; ++j) {
            int idx = j * 64 + lane;
            int r = idx / 40, cc = idx - r * 40;
            int gcol = ch0 * 5 + cc;
            float v = 0.f;
            if (gcol < 310) v = eeg[(bw + r) * 310 + gcol];
            sw[r * 41 + cc] = v;
        }
        __syncthreads();
        const int nch = (62 - ch0 < 8) ? (62 - ch0) : 8;
        for (int el = 0; el < nch; ++el) {
            const int c = ch0 + el;
            const float* owr = eeg_ow + c * 62;
            float oc = eeg_ob[c];
            #pragma unroll
            for (int d = 0; d < 62; ++d) oc = fmaf(owr[d], vbar[d], oc);
            const float* xr = sw + lane * 41 + el * 5;
            float x0 = xr[0], x1 = xr[1], x2 = xr[2], x3 = xr[3], x4 = xr[4];
            const float* cwr = ws + WS_CWT + c * 160;
            #pragma unroll
            for (int o = 0; o < 32; ++o) {
                float tt = x0 * cwr[o * 5 + 0];
                tt = fmaf(x1, cwr[o * 5 + 1], tt);
                tt = fmaf(x2, cwr[o * 5 + 2], tt);
                tt = fmaf(x3, cwr[o * 5 + 3], tt);
                tt = fmaf(x4, cwr[o * 5 + 4], tt);
                h[o] = fmaf(oc, tt, h[o]);
            }
        }
        __syncthreads();
    }

    // elu + fold into feat via A_eeg
    #pragma unroll
    for (int o = 0; o < 32; ++o) h[o] = h[o] > 0.f ? h[o] : expm1f(h[o]);

    float feat[64];
    #pragma unroll
    for (int f = 0; f < 64; ++f) {
        float acc = ws[WS_B0 + f];
        #pragma unroll
        for (int o = 0; o < 32; ++o)
            acc = fmaf(ws[WS_A_EEG + f * 32 + o], h[o], acc);
        feat[f] = acc;
    }

    // ================= EOG branch (single staged pass) =================
    // stage 64 rows x 33 cols
    for (int j = 0; j < 33; ++j) {
        int idx = j * 64 + lane;          // covers exactly 64*33 = 2112
        int r = idx / 33, cc = idx - r * 33;
        sw[r * 34 + cc] = eog[(bw + r) * 33 + cc];
    }
    __syncthreads();
    {
        float Tg[32];
        #pragma unroll
        for (int o = 0; o < 32; ++o) Tg[o] = 0.f;
        float pool = 0.f;
        for (int l2 = 0; l2 < 33; ++l2) {
            float x = sw[lane * 34 + l2];
            pool += x;
            const float* cr = ws + WS_CWOG + l2 * 32;
            #pragma unroll
            for (int o = 0; o < 32; ++o) Tg[o] = fmaf(x, cr[o], Tg[o]);
        }
        pool *= (1.f / 33.f);
        float vb2 = fmaf(pool, eog_inw[2], eog_inb[2]);
        float ob2 = fmaf(vb2, eog_ow[0], eog_ob[0]);
        #pragma unroll
        for (int o = 0; o < 32; ++o) {
            float hh = fmaf(ob2, Tg[o], eog_cb[o]);
            Tg[o] = hh > 0.f ? hh : expm1f(hh);
        }
        #pragma unroll
        for (int f = 0; f < 64; ++f) {
            float acc = feat[f];
            #pragma unroll
            for (int o = 0; o < 32; ++o)
                acc = fmaf(ws[WS_A_EOG + f * 32 + o], Tg[o], acc);
            feat[f] = acc;
        }
    }

    // ================= 2-layer norm-first transformer (seq len 1) =====
    for (int i2 = 0; i2 < 2; ++i2) {
        const float* Wa  = ws + WS_WATT + i2 * 4096;
        const float* ba  = ws + WS_BATT + i2 * 64;
        const float* s1  = tl_ln1_s + i2 * 64;
        const float* g1  = tl_ln1_b + i2 * 64;
        const float* s2  = tl_ln2_s + i2 * 64;
        const float* g2  = tl_ln2_b + i2 * 64;
        const float* w1p = tl_w1 + i2 * 16384;
        const float* bf1 = tl_b1 + i2 * 256;
        const float* w2t = ws + WS_W2T + i2 * 16384;
        const float* bf2 = tl_b2 + i2 * 64;

        float hb[64];
        // LN1
        {
            float m = 0.f;
            #pragma unroll
            for (int d = 0; d < 64; ++d) m += feat[d];
            m *= 0.015625f;
            float vv = 0.f;
            #pragma unroll
            for (int d = 0; d < 64; ++d) { float u = feat[d] - m; vv = fmaf(u, u, vv); }
            vv *= 0.015625f;
            float inv = rsqrtf(vv + 1e-5f);
            #pragma unroll
            for (int d = 0; d < 64; ++d)
                hb[d] = fmaf((feat[d] - m) * inv, s1[d], g1[d]);
        }
        // attn == folded 64x64 linear (softmax over 1 key == identity)
        #pragma unroll
        for (int c = 0; c < 64; ++c) {
            float a = ba[c];
            #pragma unroll
            for (int d = 0; d < 64; ++d) a = fmaf(Wa[c * 64 + d], hb[d], a);
            feat[c] += a;
        }
        // LN2
        {
            float m = 0.f;
            #pragma unroll
            for (int d = 0; d < 64; ++d) m += feat[d];
            m *= 0.015625f;
            float vv = 0.f;
            #pragma unroll
            for (int d = 0; d < 64; ++d) { float u = feat[d] - m; vv = fmaf(u, u, vv); }
            vv *= 0.015625f;
            float inv = rsqrtf(vv + 1e-5f);
            #pragma unroll
            for (int d = 0; d < 64; ++d)
                hb[d] = fmaf((feat[d] - m) * inv, s2[d], g2[d]);
        }
        // FFN: feat += gelu(hb @ w1.T + b1) @ w2.T + b2
        #pragma unroll
        for (int c = 0; c < 64; ++c) feat[c] += bf2[c];
        for (int j = 0; j < 256; ++j) {
            const float* wr = w1p + j * 64;
            float g = bf1[j];
            #pragma unroll
            for (int d = 0; d < 64; ++d) g = fmaf(wr[d], hb[d], g);
            g = 0.5f * g * (1.f + erff(g * 0.70710678118654752f));   // exact gelu
            const float* w2r = w2t + j * 64;
            #pragma unroll
            for (int c = 0; c < 64; ++c) feat[c] = fmaf(g, w2r[c], feat[c]);
        }
    }

    // ================= final LN + classifier =================
    {
        float m = 0.f;
        #pragma unroll
        for (int d = 0; d < 64; ++d) m += feat[d];
        m *= 0.015625f;
        float vv = 0.f;
        #pragma unroll
        for (int d = 0; d < 64; ++d) { float u = feat[d] - m; vv = fmaf(u, u, vv); }
        vv *= 0.015625f;
        float inv = rsqrtf(vv + 1e-5f);
        float o0 = cls_b[0], o1 = cls_b[1], o2 = cls_b[2];
        #pragma unroll
        for (int d = 0; d < 64; ++d) {
            float n = fmaf((feat[d] - m) * inv, fn_s[d], fn_b[d]);
            o0 = fmaf(n, cls_w[d], o0);
            o1 = fmaf(n, cls_w[64 + d], o1);
            o2 = fmaf(n, cls_w[128 + d], o2);
        }
        float* op = out + b * 3;
        op[0] = o0; op[1] = o1; op[2] = o2;
    }
}

extern "C" void kernel_launch(void* const* d_in, const int* in_sizes, int n_in,
                              void* d_out, int out_size, void* d_ws, size_t ws_size,
                              hipStream_t stream) {
    const float* eeg      = (const float*)d_in[0];
    const float* eog      = (const float*)d_in[1];
    const float* eeg_inw  = (const float*)d_in[2];
    const float* eeg_inb  = (const float*)d_in[3];
    const float* eeg_ow   = (const float*)d_in[4];
    const float* eeg_ob   = (const float*)d_in[5];
    const float* eog_inw  = (const float*)d_in[6];
    const float* eog_inb  = (const float*)d_in[7];
    const float* eog_ow   = (const float*)d_in[8];
    const float* eog_ob   = (const float*)d_in[9];
    const float* eeg_cw   = (const float*)d_in[10];
    const float* eeg_cb   = (const float*)d_in[11];
    const float* eeg_fw   = (const float*)d_in[12];
    const float* eeg_fb   = (const float*)d_in[13];
    const float* eog_cw   = (const float*)d_in[14];
    const float* eog_cb   = (const float*)d_in[15];
    const float* eog_fw   = (const float*)d_in[16];
    const float* eog_fb   = (const float*)d_in[17];
    const float* fus_w    = (const float*)d_in[18];
    const float* fus_b    = (const float*)d_in[19];
    const float* tl_ln1_s = (const float*)d_in[20];
    const float* tl_ln1_b = (const float*)d_in[21];
    const float* tl_inw   = (const float*)d_in[22];
    const float* tl_inb   = (const float*)d_in[23];
    const float* tl_ow    = (const float*)d_in[24];
    const float* tl_ob    = (const float*)d_in[25];
    const float* tl_ln2_s = (const float*)d_in[26];
    const float* tl_ln2_b = (const float*)d_in[27];
    const float* tl_w1    = (const float*)d_in[28];
    const float* tl_b1    = (const float*)d_in[29];
    const float* tl_w2    = (const float*)d_in[30];
    const float* tl_b2    = (const float*)d_in[31];
    const float* fn_s     = (const float*)d_in[32];
    const float* fn_b     = (const float*)d_in[33];
    const float* cls_w    = (const float*)d_in[34];
    const float* cls_b    = (const float*)d_in[35];
    float* ws  = (float*)d_ws;
    float* out = (float*)d_out;

    hipLaunchKernelGGL(mcaf_pre, dim3(8), dim3(256), 0, stream,
                       eeg_inw, eeg_cw, eeg_fw, eeg_fb, eog_cw, eog_fw, eog_fb,
                       fus_w, fus_b, tl_inw, tl_inb, tl_ow, tl_ob, tl_w2, ws);

    hipLaunchKernelGGL(mcaf_main, dim3(NB / 256), dim3(256), 0, stream,
                       eeg, eog, eeg_inb, eeg_ow, eeg_ob,
                       eog_inw, eog_inb, eog_ow, eog_ob,
                       eeg_cb, eog_cb,
                       tl_ln1_s, tl_ln1_b, tl_ln2_s, tl_ln2_b,
                       tl_w1, tl_b1, tl_b2,
                       fn_s, fn_b, cls_w, cls_b,
                       ws, out);
}